// Round 17
// baseline (583.543 us; speedup 1.0000x reference)
//
#include <hip/hip_runtime.h>
#include <math.h>

#define D_   2048
#define E_   16
#define H_   1024
#define KSEL 4
#define B_   4096
#define CAP  4096

typedef short bf16x8_t __attribute__((ext_vector_type(8)));
typedef float f32x4_t  __attribute__((ext_vector_type(4)));

__device__ __forceinline__ unsigned short f2bf(float f) {
  unsigned u = __float_as_uint(f);
  u += 0x7FFFu + ((u >> 16) & 1u);   // RNE
  return (unsigned short)(u >> 16);
}

__device__ __forceinline__ float bf2f(unsigned short h) {
  unsigned u = (unsigned)h << 16;
  return __uint_as_float(u);
}

__device__ __forceinline__ void gld16(const void* g, void* l) {
  __builtin_amdgcn_global_load_lds(
      (const __attribute__((address_space(1))) unsigned int*)g,
      (__attribute__((address_space(3))) unsigned int*)l, 16, 0, 0);
}

// ---- fused weight prep: Wr transpose + W1/W2 transpose-convert, 2-tile ----
// pipelined blocks: BOTH tiles' global loads issued up front (regs), t1's
// loads fly during t0's LDS/convert/store phase (counted vmcnt keeps them
// outstanding). blockIdx: [0,128) transr; [128,8320) -> 2 W-tiles each.
__global__ __launch_bounds__(256) void k_prepw(
    const float* __restrict__ Wr, float* __restrict__ wrT,
    const float* __restrict__ W1, unsigned short* __restrict__ W1t,
    const float* __restrict__ W2, unsigned short* __restrict__ W2t) {
  __shared__ float tile[64][65];
  int b = blockIdx.x;
  int w = threadIdx.x;
  if (b < 128) {
    int i = b * 256 + w;                     // coalesced read over D*E
    int d = i >> 4, e = i & 15;
    wrT[e * D_ + d] = Wr[i];                 // 16-stream write; L2 absorbs
    return;
  }
  int g0 = (b - 128) * 2;
  const float* src[2]; unsigned short* dst[2];
  int RR[2], CC[2], r0t[2], c0t[2];
#pragma unroll
  for (int tt = 0; tt < 2; tt++) {
    int g = g0 + tt;
    if (g < 8192) {                          // W1 [E][2048][1024] -> [E][1024][2048]
      int e = g >> 9, rem = g & 511;
      src[tt] = W1 + (size_t)e * D_ * H_;
      dst[tt] = W1t + (size_t)e * D_ * H_;
      RR[tt] = 2048; CC[tt] = 1024;
      r0t[tt] = (rem >> 4) * 64; c0t[tt] = (rem & 15) * 64;
    } else {                                 // W2 [E][1024][2048] -> [E][2048][1024]
      int g2 = g - 8192;
      int e = g2 >> 9, rem = g2 & 511;
      src[tt] = W2 + (size_t)e * D_ * H_;
      dst[tt] = W2t + (size_t)e * D_ * H_;
      RR[tt] = 1024; CC[tt] = 2048;
      r0t[tt] = (rem >> 5) * 64; c0t[tt] = (rem & 31) * 64;
    }
  }
  int cf4 = w & 15, rr = w >> 4;
  float4 v0[4], v1[4];
#pragma unroll
  for (int p = 0; p < 4; p++)
    v0[p] = *(const float4*)(src[0] + (size_t)(r0t[0] + p * 16 + rr) * CC[0] + c0t[0] + cf4 * 4);
#pragma unroll
  for (int p = 0; p < 4; p++)
    v1[p] = *(const float4*)(src[1] + (size_t)(r0t[1] + p * 16 + rr) * CC[1] + c0t[1] + cf4 * 4);
  // ---- tile 0 ----
#pragma unroll
  for (int p = 0; p < 4; p++) {
    int r = p * 16 + rr;
    tile[r][cf4 * 4 + 0] = v0[p].x;
    tile[r][cf4 * 4 + 1] = v0[p].y;
    tile[r][cf4 * 4 + 2] = v0[p].z;
    tile[r][cf4 * 4 + 3] = v0[p].w;
  }
  __syncthreads();
#pragma unroll
  for (int it = 0; it < 8; it++) {
    int idx = it * 256 + w;
    int i = idx >> 5, rp = idx & 31;
    ushort2 v;
    v.x = f2bf(tile[2 * rp][i]);
    v.y = f2bf(tile[2 * rp + 1][i]);
    *(ushort2*)(dst[0] + (size_t)(c0t[0] + i) * RR[0] + r0t[0] + 2 * rp) = v;
  }
  __syncthreads();
  // ---- tile 1 ----
#pragma unroll
  for (int p = 0; p < 4; p++) {
    int r = p * 16 + rr;
    tile[r][cf4 * 4 + 0] = v1[p].x;
    tile[r][cf4 * 4 + 1] = v1[p].y;
    tile[r][cf4 * 4 + 2] = v1[p].z;
    tile[r][cf4 * 4 + 3] = v1[p].w;
  }
  __syncthreads();
#pragma unroll
  for (int it = 0; it < 8; it++) {
    int idx = it * 256 + w;
    int i = idx >> 5, rp = idx & 31;
    ushort2 v;
    v.x = f2bf(tile[2 * rp][i]);
    v.y = f2bf(tile[2 * rp + 1][i]);
    *(ushort2*)(dst[1] + (size_t)(c0t[1] + i) * RR[1] + r0t[1] + 2 * rp) = v;
  }
}

// ------- fused: router (logits/top4/softmax -> tops/topw) + x->bf16 store ------
__global__ __launch_bounds__(256) void k_router(
    const float* __restrict__ x, const float* __restrict__ wrT, const float* __restrict__ br,
    unsigned short* __restrict__ xb, int* __restrict__ tops, float* __restrict__ topw) {
  int wid = threadIdx.x >> 6, lane = threadIdx.x & 63;
  int t = blockIdx.x * 4 + wid;
  float acc[E_];
#pragma unroll
  for (int e = 0; e < E_; e++) acc[e] = 0.f;
  const float4* xr = (const float4*)(x + (size_t)t * D_);
  ushort4* xbw = (ushort4*)(xb + (size_t)t * D_);
#pragma unroll
  for (int j = 0; j < D_ / 256; j++) {
    float4 xv = xr[j * 64 + lane];
    ushort4 o;
    o.x = f2bf(xv.x); o.y = f2bf(xv.y); o.z = f2bf(xv.z); o.w = f2bf(xv.w);
    xbw[j * 64 + lane] = o;
#pragma unroll
    for (int e = 0; e < E_; e++) {
      float4 wv = ((const float4*)(wrT + (size_t)e * D_))[j * 64 + lane];
      acc[e] += xv.x * wv.x + xv.y * wv.y + xv.z * wv.z + xv.w * wv.w;
    }
  }
#pragma unroll
  for (int e = 0; e < E_; e++) {
    float v = acc[e];
    for (int m = 32; m >= 1; m >>= 1) v += __shfl_xor(v, m);
    acc[e] = v;
  }
  if (lane == 0) {
    float lg[E_];
#pragma unroll
    for (int e = 0; e < E_; e++) lg[e] = acc[e] + br[e];
    unsigned used = 0; int sel[KSEL]; float sv[KSEL];
    for (int k = 0; k < KSEL; k++) {
      float best = -1e30f; int bi = 0;
      for (int e = 0; e < E_; e++)
        if (!((used >> e) & 1u) && lg[e] > best) { best = lg[e]; bi = e; }
      used |= 1u << bi; sel[k] = bi; sv[k] = best;
    }
    float mx = sv[0], s = 0.f, w[KSEL];
    for (int k = 0; k < KSEL; k++) { w[k] = expf(sv[k] - mx); s += w[k]; }
    float inv = 1.f / s;
    int4 ti; float4 tw;
    ti.x = sel[0]; ti.y = sel[1]; ti.z = sel[2]; ti.w = sel[3];
    tw.x = w[0] * inv; tw.y = w[1] * inv; tw.z = w[2] * inv; tw.w = w[3] * inv;
    ((int4*)tops)[t] = ti;
    ((float4*)topw)[t] = tw;
  }
}

// ------- build per-expert token lists + inverse map (deterministic, no atomics)
__global__ __launch_bounds__(256) void k_build(
    const int* __restrict__ tops, const float* __restrict__ topw,
    int* __restrict__ counts, int* __restrict__ ids, float* __restrict__ wts,
    int* __restrict__ inv) {
  int e = blockIdx.x;
  int tid = threadIdx.x, lane = tid & 63, wid = tid >> 6;
  __shared__ int wsum[4];
  __shared__ int red[4];
  int base = 0;
  int pre = 0;
  for (int c = 0; c < B_; c += 256) {
    int t = c + tid;
    int4 tk = ((const int4*)tops)[t];
    pre += (tk.x < e) + (tk.y < e) + (tk.z < e) + (tk.w < e);
    int k = -1;
    if (tk.x == e) k = 0; else if (tk.y == e) k = 1;
    else if (tk.z == e) k = 2; else if (tk.w == e) k = 3;
    unsigned long long mask = __ballot(k >= 0);
    int myoff = __popcll(mask & ((1ull << lane) - 1ull));
    if (lane == 0) wsum[wid] = __popcll(mask);
    __syncthreads();
    int woff = 0;
#pragma unroll
    for (int i = 0; i < 4; i++) if (i < wid) woff += wsum[i];
    int ctotal = wsum[0] + wsum[1] + wsum[2] + wsum[3];
    if (k >= 0) {
      int slot = base + woff + myoff;
      ids[e * CAP + slot] = t;
      wts[e * CAP + slot] = topw[t * 4 + k];
    }
    base += ctotal;
    __syncthreads();
  }
  if (tid == 0) counts[e] = base;
  for (int m = 32; m >= 1; m >>= 1) pre += __shfl_xor(pre, m);
  if (lane == 0) red[wid] = pre;
  __syncthreads();
  int offe = red[0] + red[1] + red[2] + red[3];
  for (int s = tid; s < base; s += 256) {
    int t = ids[e * CAP + s];
    int4 tk = ((const int4*)tops)[t];
    int k = (tk.x == e) ? 0 : (tk.y == e) ? 1 : (tk.z == e) ? 2 : 3;
    inv[t * 4 + k] = offe + s;
  }
}

// ---------------- gather: out[t] = x[t] + sum_k ybuf[inv[t][k]] ----------------
__global__ __launch_bounds__(256) void k_gather(
    const float* __restrict__ x, const unsigned short* __restrict__ ybuf,
    const int* __restrict__ inv, float* __restrict__ out) {
  int t = blockIdx.x;
  int4 iv = ((const int4*)inv)[t];
  const ushort4* y0 = (const ushort4*)(ybuf + (size_t)iv.x * D_);
  const ushort4* y1 = (const ushort4*)(ybuf + (size_t)iv.y * D_);
  const ushort4* y2 = (const ushort4*)(ybuf + (size_t)iv.z * D_);
  const ushort4* y3 = (const ushort4*)(ybuf + (size_t)iv.w * D_);
  const float4* xr = (const float4*)(x + (size_t)t * D_);
  float4* orow = (float4*)(out + (size_t)t * D_);
#pragma unroll
  for (int i = threadIdx.x; i < D_ / 4; i += 256) {
    float4 v = xr[i];
    ushort4 a = y0[i], b = y1[i], c = y2[i], d = y3[i];
    v.x += bf2f(a.x) + bf2f(b.x) + bf2f(c.x) + bf2f(d.x);
    v.y += bf2f(a.y) + bf2f(b.y) + bf2f(c.y) + bf2f(d.y);
    v.z += bf2f(a.z) + bf2f(b.z) + bf2f(c.z) + bf2f(d.z);
    v.w += bf2f(a.w) + bf2f(b.w) + bf2f(c.w) + bf2f(d.w);
    orow[i] = v;
  }
}

// ====== GEMM: BM=BN=128, BK=64, 4 waves, now 4 blocks/CU (256,4) ======
// One tile per block; grid = worst-case tile count; HW backfill balances.
// Expert-outer, slab-mid, row-inner tile index; chunked XCD swizzle.
// Co-residency is the proven mechanism (R10->R11 2->3 blocks = -23%): 4x32KB
// LDS = 128 <= 160KB, VGPR 76 <= 128/wave cap at 16 waves/CU -> no spill.

// ---------------- GEMM1: h = relu(X[ids] @ W1t^T + b1), bf16 out ----------------
__global__ __launch_bounds__(256, 4) void k_gemm1(
    const unsigned short* __restrict__ xb,   // [B][D] bf16
    const unsigned short* __restrict__ w1t,  // [E][H][D] bf16
    const float* __restrict__ b1,            // [E][H]
    const int* __restrict__ ids, const int* __restrict__ counts,
    unsigned short* __restrict__ hbuf)       // [sum cnt][H] bf16
{
  __shared__ unsigned short As[128 * 64];
  __shared__ unsigned short Bs[128 * 64];
  const int NS = H_ / 128;                   // 8 col slabs
  int cnts[E_], offsv[E_], rowt[E_], cumt[E_];
  int s = 0, tcum = 0;
#pragma unroll
  for (int e = 0; e < E_; e++) {
    cnts[e] = counts[e];
    offsv[e] = s; s += cnts[e];
    rowt[e] = (cnts[e] + 127) >> 7;
    cumt[e] = tcum; tcum += rowt[e] * NS;
  }
  int totalTiles = tcum;
  int bswz = (blockIdx.x & 7) * (gridDim.x >> 3) + (blockIdx.x >> 3);
  if (bswz >= totalTiles) return;
  int tile = bswz;
  int tid = threadIdx.x, lane = tid & 63, wid = tid >> 6;
  int wr = wid >> 1, wc = wid & 1;
  int cr = lane >> 3, slot = lane & 7;
  int sw = (slot ^ cr) << 3;
  int hi = lane >> 4, cl = lane & 15;

  int e = 0;
  while (e < E_ - 1 && tile >= cumt[e + 1]) e++;
  int local = tile - cumt[e];
  int slab = local / rowt[e];
  int rt = local - slab * rowt[e];
  int n0 = slab << 7;
  int cnt = cnts[e];
  int r0 = rt << 7;

  const unsigned short* a_src[4];
  const unsigned short* b_src[4];
  const unsigned short* wbase = w1t + (size_t)e * H_ * D_;
#pragma unroll
  for (int i = 0; i < 4; i++) {
    int chunk = wid * 4 + i;
    int rr = r0 + chunk * 8 + cr;
    int rc = min(rr, cnt - 1);
    int tok = ids[e * CAP + rc];
    a_src[i] = xb + (size_t)tok * D_ + sw;
    b_src[i] = wbase + (size_t)(n0 + chunk * 8 + cr) * D_ + sw;
  }
  f32x4_t acc[4][4];
#pragma unroll
  for (int m = 0; m < 4; m++)
#pragma unroll
    for (int n = 0; n < 4; n++) acc[m][n] = (f32x4_t){0.f, 0.f, 0.f, 0.f};

  for (int kt = 0; kt < D_; kt += 64) {
#pragma unroll
    for (int i = 0; i < 4; i++) {
      gld16(a_src[i] + kt, As + (wid * 4 + i) * 512);
      gld16(b_src[i] + kt, Bs + (wid * 4 + i) * 512);
    }
    __syncthreads();
#pragma unroll
    for (int kb = 0; kb < 2; kb++) {
      bf16x8_t af[4], bfr[4];
#pragma unroll
      for (int m = 0; m < 4; m++) {
        int row = wr * 64 + m * 16 + (lane & 15);
        int ss = (kb * 4 + (lane >> 4)) ^ (row & 7);
        af[m] = *(const bf16x8_t*)(As + row * 64 + ss * 8);
      }
#pragma unroll
      for (int n = 0; n < 4; n++) {
        int row = wc * 64 + n * 16 + (lane & 15);
        int ss = (kb * 4 + (lane >> 4)) ^ (row & 7);
        bfr[n] = *(const bf16x8_t*)(Bs + row * 64 + ss * 8);
      }
#pragma unroll
      for (int m = 0; m < 4; m++)
#pragma unroll
        for (int n = 0; n < 4; n++)
          acc[m][n] = __builtin_amdgcn_mfma_f32_16x16x32_bf16(af[m], bfr[n], acc[m][n], 0, 0, 0);
    }
    __syncthreads();
  }
  int offe = offsv[e];
  float bias[4];
#pragma unroll
  for (int n = 0; n < 4; n++)
    bias[n] = b1[e * H_ + n0 + wc * 64 + n * 16 + cl];
#pragma unroll
  for (int m = 0; m < 4; m++)
#pragma unroll
    for (int j = 0; j < 4; j++) {
      int sr = r0 + wr * 64 + m * 16 + hi * 4 + j;
      if (sr < cnt) {
        size_t rowb = (size_t)(offe + sr) * H_;
#pragma unroll
        for (int n = 0; n < 4; n++) {
          int col = n0 + wc * 64 + n * 16 + cl;
          float v = acc[m][n][j] + bias[n];
          v = v > 0.f ? v : 0.f;
          hbuf[rowb + col] = f2bf(v);
        }
      }
    }
}

// ------ GEMM2: ybuf[gslot] = w * (h @ W2t^T + b2)  (bf16 streaming stores) ------
__global__ __launch_bounds__(256, 4) void k_gemm2(
    const unsigned short* __restrict__ hbuf, // [sum cnt][H] bf16
    const unsigned short* __restrict__ w2t,  // [E][D][H] bf16
    const float* __restrict__ b2,            // [E][D]
    const float* __restrict__ wts,
    const int* __restrict__ counts,
    unsigned short* __restrict__ ybuf)       // [sum cnt][D] bf16
{
  __shared__ unsigned short As[128 * 64];
  __shared__ unsigned short Bs[128 * 64];
  const int NS = D_ / 128;                   // 16 col slabs
  int cnts[E_], offsv[E_], rowt[E_], cumt[E_];
  int s = 0, tcum = 0;
#pragma unroll
  for (int e = 0; e < E_; e++) {
    cnts[e] = counts[e];
    offsv[e] = s; s += cnts[e];
    rowt[e] = (cnts[e] + 127) >> 7;
    cumt[e] = tcum; tcum += rowt[e] * NS;
  }
  int totalTiles = tcum;
  int bswz = (blockIdx.x & 7) * (gridDim.x >> 3) + (blockIdx.x >> 3);
  if (bswz >= totalTiles) return;
  int tile = bswz;
  int tid = threadIdx.x, lane = tid & 63, wid = tid >> 6;
  int wr = wid >> 1, wc = wid & 1;
  int cr = lane >> 3, slot = lane & 7;
  int sw = (slot ^ cr) << 3;
  int hi = lane >> 4, cl = lane & 15;

  int e = 0;
  while (e < E_ - 1 && tile >= cumt[e + 1]) e++;
  int local = tile - cumt[e];
  int slab = local / rowt[e];
  int rt = local - slab * rowt[e];
  int n0 = slab << 7;
  int cnt = cnts[e];
  int r0 = rt << 7;
  int offe = offsv[e];

  const unsigned short* a_src[4];
  const unsigned short* b_src[4];
  const unsigned short* wbase = w2t + (size_t)e * D_ * H_;
#pragma unroll
  for (int i = 0; i < 4; i++) {
    int chunk = wid * 4 + i;
    int rr = r0 + chunk * 8 + cr;
    int rc = min(rr, cnt - 1);
    a_src[i] = hbuf + (size_t)(offe + rc) * H_ + sw;
    b_src[i] = wbase + (size_t)(n0 + chunk * 8 + cr) * H_ + sw;
  }
  f32x4_t acc[4][4];
#pragma unroll
  for (int m = 0; m < 4; m++)
#pragma unroll
    for (int n = 0; n < 4; n++) acc[m][n] = (f32x4_t){0.f, 0.f, 0.f, 0.f};

  for (int kt = 0; kt < H_; kt += 64) {
#pragma unroll
    for (int i = 0; i < 4; i++) {
      gld16(a_src[i] + kt, As + (wid * 4 + i) * 512);
      gld16(b_src[i] + kt, Bs + (wid * 4 + i) * 512);
    }
    __syncthreads();
#pragma unroll
    for (int kb = 0; kb < 2; kb++) {
      bf16x8_t af[4], bfr[4];
#pragma unroll
      for (int m = 0; m < 4; m++) {
        int row = wr * 64 + m * 16 + (lane & 15);
        int ss = (kb * 4 + (lane >> 4)) ^ (row & 7);
        af[m] = *(const bf16x8_t*)(As + row * 64 + ss * 8);
      }
#pragma unroll
      for (int n = 0; n < 4; n++) {
        int row = wc * 64 + n * 16 + (lane & 15);
        int ss = (kb * 4 + (lane >> 4)) ^ (row & 7);
        bfr[n] = *(const bf16x8_t*)(Bs + row * 64 + ss * 8);
      }
#pragma unroll
      for (int m = 0; m < 4; m++)
#pragma unroll
        for (int n = 0; n < 4; n++)
          acc[m][n] = __builtin_amdgcn_mfma_f32_16x16x32_bf16(af[m], bfr[n], acc[m][n], 0, 0, 0);
    }
    __syncthreads();
  }
  float bias[4];
#pragma unroll
  for (int n = 0; n < 4; n++)
    bias[n] = b2[e * D_ + n0 + wc * 64 + n * 16 + cl];
#pragma unroll
  for (int m = 0; m < 4; m++)
#pragma unroll
    for (int j = 0; j < 4; j++) {
      int sr = r0 + wr * 64 + m * 16 + hi * 4 + j;
      if (sr < cnt) {
        float w = wts[e * CAP + sr];
        unsigned short* yrow = ybuf + (size_t)(offe + sr) * D_;
#pragma unroll
        for (int n = 0; n < 4; n++) {
          int col = n0 + wc * 64 + n * 16 + cl;
          yrow[col] = f2bf(w * (acc[m][n][j] + bias[n]));
        }
      }
    }
}

extern "C" void kernel_launch(void* const* d_in, const int* in_sizes, int n_in,
                              void* d_out, int out_size, void* d_ws, size_t ws_size,
                              hipStream_t stream) {
  const float* x  = (const float*)d_in[0];
  const float* W1 = (const float*)d_in[1];
  const float* b1 = (const float*)d_in[2];
  const float* W2 = (const float*)d_in[3];
  const float* b2 = (const float*)d_in[4];
  const float* Wr = (const float*)d_in[5];
  const float* br = (const float*)d_in[6];
  float* out = (float*)d_out;
  char* ws = (char*)d_ws;
  // workspace layout (~176.9 MiB total). ybuf ALIASES W1t (dead after gemm1).
  unsigned short* W1t  = (unsigned short*)(ws);                // 67108864 B [E][H][D] bf16
  unsigned short* ybuf = (unsigned short*)(ws);                // 67108864 B [16384][D] bf16
  unsigned short* W2t  = (unsigned short*)(ws + 67108864);     // 67108864 B [E][D][H] bf16
  unsigned short* xb   = (unsigned short*)(ws + 134217728);    // 16777216 B [B][D] bf16
  unsigned short* hb   = (unsigned short*)(ws + 150994944);    // 33554432 B [B*K][H] bf16
  int*   ids    = (int*)  (ws + 184549376);                    // 262144 B
  float* wts    = (float*)(ws + 184811520);                    // 262144 B
  int*   counts = (int*)  (ws + 185073664);                    // 64 B
  float* wrT    = (float*)(ws + 185073728);                    // 131072 B [E][D] f32
  int*   tops   = (int*)  (ws + 185204800);                    // 65536 B [B][4]
  float* topw   = (float*)(ws + 185270336);                    // 65536 B [B][4]
  int*   inv    = (int*)  (ws + 185335872);                    // 65536 B [B][4]

  k_prepw<<<8320, 256, 0, stream>>>(Wr, wrT, W1, W1t, W2, W2t);
  k_router<<<1024, 256, 0, stream>>>(x, wrT, br, xb, tops, topw);
  k_build<<<16, 256, 0, stream>>>(tops, topw, counts, ids, wts, inv);
  k_gemm1<<<1152, 256, 0, stream>>>(xb, W1t, b1, ids, counts, hb);
  k_gemm2<<<2304, 256, 0, stream>>>(hb, W2t, b2, wts, counts, ybuf);
  k_gather<<<4096, 256, 0, stream>>>(x, ybuf, inv, out);
}

// Round 18
// 386.801 us; speedup vs baseline: 1.5086x; 1.5086x over previous
//
#include <hip/hip_runtime.h>
#include <math.h>

#define D_   2048
#define E_   16
#define H_   1024
#define KSEL 4
#define B_   4096
#define CAP  4096

typedef short bf16x8_t __attribute__((ext_vector_type(8)));
typedef float f32x4_t  __attribute__((ext_vector_type(4)));

__device__ __forceinline__ unsigned short f2bf(float f) {
  unsigned u = __float_as_uint(f);
  u += 0x7FFFu + ((u >> 16) & 1u);   // RNE
  return (unsigned short)(u >> 16);
}

__device__ __forceinline__ float bf2f(unsigned short h) {
  unsigned u = (unsigned)h << 16;
  return __uint_as_float(u);
}

__device__ __forceinline__ void gld16(const void* g, void* l) {
  __builtin_amdgcn_global_load_lds(
      (const __attribute__((address_space(1))) unsigned int*)g,
      (__attribute__((address_space(3))) unsigned int*)l, 16, 0, 0);
}

// ---- fused weight prep: Wr transpose + W1/W2 transpose-convert, 2-tile ----
// pipelined blocks: BOTH tiles' global loads issued up front (regs), t1's
// loads fly during t0's LDS/convert/store phase (counted vmcnt keeps them
// outstanding). blockIdx: [0,128) transr; [128,8320) -> 2 W-tiles each.
__global__ __launch_bounds__(256) void k_prepw(
    const float* __restrict__ Wr, float* __restrict__ wrT,
    const float* __restrict__ W1, unsigned short* __restrict__ W1t,
    const float* __restrict__ W2, unsigned short* __restrict__ W2t) {
  __shared__ float tile[64][65];
  int b = blockIdx.x;
  int w = threadIdx.x;
  if (b < 128) {
    int i = b * 256 + w;                     // coalesced read over D*E
    int d = i >> 4, e = i & 15;
    wrT[e * D_ + d] = Wr[i];                 // 16-stream write; L2 absorbs
    return;
  }
  int g0 = (b - 128) * 2;
  const float* src[2]; unsigned short* dst[2];
  int RR[2], CC[2], r0t[2], c0t[2];
#pragma unroll
  for (int tt = 0; tt < 2; tt++) {
    int g = g0 + tt;
    if (g < 8192) {                          // W1 [E][2048][1024] -> [E][1024][2048]
      int e = g >> 9, rem = g & 511;
      src[tt] = W1 + (size_t)e * D_ * H_;
      dst[tt] = W1t + (size_t)e * D_ * H_;
      RR[tt] = 2048; CC[tt] = 1024;
      r0t[tt] = (rem >> 4) * 64; c0t[tt] = (rem & 15) * 64;
    } else {                                 // W2 [E][1024][2048] -> [E][2048][1024]
      int g2 = g - 8192;
      int e = g2 >> 9, rem = g2 & 511;
      src[tt] = W2 + (size_t)e * D_ * H_;
      dst[tt] = W2t + (size_t)e * D_ * H_;
      RR[tt] = 1024; CC[tt] = 2048;
      r0t[tt] = (rem >> 5) * 64; c0t[tt] = (rem & 31) * 64;
    }
  }
  int cf4 = w & 15, rr = w >> 4;
  float4 v0[4], v1[4];
#pragma unroll
  for (int p = 0; p < 4; p++)
    v0[p] = *(const float4*)(src[0] + (size_t)(r0t[0] + p * 16 + rr) * CC[0] + c0t[0] + cf4 * 4);
#pragma unroll
  for (int p = 0; p < 4; p++)
    v1[p] = *(const float4*)(src[1] + (size_t)(r0t[1] + p * 16 + rr) * CC[1] + c0t[1] + cf4 * 4);
  // ---- tile 0 ----
#pragma unroll
  for (int p = 0; p < 4; p++) {
    int r = p * 16 + rr;
    tile[r][cf4 * 4 + 0] = v0[p].x;
    tile[r][cf4 * 4 + 1] = v0[p].y;
    tile[r][cf4 * 4 + 2] = v0[p].z;
    tile[r][cf4 * 4 + 3] = v0[p].w;
  }
  __syncthreads();
#pragma unroll
  for (int it = 0; it < 8; it++) {
    int idx = it * 256 + w;
    int i = idx >> 5, rp = idx & 31;
    ushort2 v;
    v.x = f2bf(tile[2 * rp][i]);
    v.y = f2bf(tile[2 * rp + 1][i]);
    *(ushort2*)(dst[0] + (size_t)(c0t[0] + i) * RR[0] + r0t[0] + 2 * rp) = v;
  }
  __syncthreads();
  // ---- tile 1 ----
#pragma unroll
  for (int p = 0; p < 4; p++) {
    int r = p * 16 + rr;
    tile[r][cf4 * 4 + 0] = v1[p].x;
    tile[r][cf4 * 4 + 1] = v1[p].y;
    tile[r][cf4 * 4 + 2] = v1[p].z;
    tile[r][cf4 * 4 + 3] = v1[p].w;
  }
  __syncthreads();
#pragma unroll
  for (int it = 0; it < 8; it++) {
    int idx = it * 256 + w;
    int i = idx >> 5, rp = idx & 31;
    ushort2 v;
    v.x = f2bf(tile[2 * rp][i]);
    v.y = f2bf(tile[2 * rp + 1][i]);
    *(ushort2*)(dst[1] + (size_t)(c0t[1] + i) * RR[1] + r0t[1] + 2 * rp) = v;
  }
}

// ------- fused: router (logits/top4/softmax -> tops/topw) + x->bf16 store ------
__global__ __launch_bounds__(256) void k_router(
    const float* __restrict__ x, const float* __restrict__ wrT, const float* __restrict__ br,
    unsigned short* __restrict__ xb, int* __restrict__ tops, float* __restrict__ topw) {
  int wid = threadIdx.x >> 6, lane = threadIdx.x & 63;
  int t = blockIdx.x * 4 + wid;
  float acc[E_];
#pragma unroll
  for (int e = 0; e < E_; e++) acc[e] = 0.f;
  const float4* xr = (const float4*)(x + (size_t)t * D_);
  ushort4* xbw = (ushort4*)(xb + (size_t)t * D_);
#pragma unroll
  for (int j = 0; j < D_ / 256; j++) {
    float4 xv = xr[j * 64 + lane];
    ushort4 o;
    o.x = f2bf(xv.x); o.y = f2bf(xv.y); o.z = f2bf(xv.z); o.w = f2bf(xv.w);
    xbw[j * 64 + lane] = o;
#pragma unroll
    for (int e = 0; e < E_; e++) {
      float4 wv = ((const float4*)(wrT + (size_t)e * D_))[j * 64 + lane];
      acc[e] += xv.x * wv.x + xv.y * wv.y + xv.z * wv.z + xv.w * wv.w;
    }
  }
#pragma unroll
  for (int e = 0; e < E_; e++) {
    float v = acc[e];
    for (int m = 32; m >= 1; m >>= 1) v += __shfl_xor(v, m);
    acc[e] = v;
  }
  if (lane == 0) {
    float lg[E_];
#pragma unroll
    for (int e = 0; e < E_; e++) lg[e] = acc[e] + br[e];
    unsigned used = 0; int sel[KSEL]; float sv[KSEL];
    for (int k = 0; k < KSEL; k++) {
      float best = -1e30f; int bi = 0;
      for (int e = 0; e < E_; e++)
        if (!((used >> e) & 1u) && lg[e] > best) { best = lg[e]; bi = e; }
      used |= 1u << bi; sel[k] = bi; sv[k] = best;
    }
    float mx = sv[0], s = 0.f, w[KSEL];
    for (int k = 0; k < KSEL; k++) { w[k] = expf(sv[k] - mx); s += w[k]; }
    float inv = 1.f / s;
    int4 ti; float4 tw;
    ti.x = sel[0]; ti.y = sel[1]; ti.z = sel[2]; ti.w = sel[3];
    tw.x = w[0] * inv; tw.y = w[1] * inv; tw.z = w[2] * inv; tw.w = w[3] * inv;
    ((int4*)tops)[t] = ti;
    ((float4*)topw)[t] = tw;
  }
}

// ------- build per-expert token lists + inverse map (deterministic, no atomics)
__global__ __launch_bounds__(256) void k_build(
    const int* __restrict__ tops, const float* __restrict__ topw,
    int* __restrict__ counts, int* __restrict__ ids, float* __restrict__ wts,
    int* __restrict__ inv) {
  int e = blockIdx.x;
  int tid = threadIdx.x, lane = tid & 63, wid = tid >> 6;
  __shared__ int wsum[4];
  __shared__ int red[4];
  int base = 0;
  int pre = 0;
  for (int c = 0; c < B_; c += 256) {
    int t = c + tid;
    int4 tk = ((const int4*)tops)[t];
    pre += (tk.x < e) + (tk.y < e) + (tk.z < e) + (tk.w < e);
    int k = -1;
    if (tk.x == e) k = 0; else if (tk.y == e) k = 1;
    else if (tk.z == e) k = 2; else if (tk.w == e) k = 3;
    unsigned long long mask = __ballot(k >= 0);
    int myoff = __popcll(mask & ((1ull << lane) - 1ull));
    if (lane == 0) wsum[wid] = __popcll(mask);
    __syncthreads();
    int woff = 0;
#pragma unroll
    for (int i = 0; i < 4; i++) if (i < wid) woff += wsum[i];
    int ctotal = wsum[0] + wsum[1] + wsum[2] + wsum[3];
    if (k >= 0) {
      int slot = base + woff + myoff;
      ids[e * CAP + slot] = t;
      wts[e * CAP + slot] = topw[t * 4 + k];
    }
    base += ctotal;
    __syncthreads();
  }
  if (tid == 0) counts[e] = base;
  for (int m = 32; m >= 1; m >>= 1) pre += __shfl_xor(pre, m);
  if (lane == 0) red[wid] = pre;
  __syncthreads();
  int offe = red[0] + red[1] + red[2] + red[3];
  for (int s = tid; s < base; s += 256) {
    int t = ids[e * CAP + s];
    int4 tk = ((const int4*)tops)[t];
    int k = (tk.x == e) ? 0 : (tk.y == e) ? 1 : (tk.z == e) ? 2 : 3;
    inv[t * 4 + k] = offe + s;
  }
}

// ---------------- gather: out[t] = x[t] + sum_k ybuf[inv[t][k]] ----------------
__global__ __launch_bounds__(256) void k_gather(
    const float* __restrict__ x, const unsigned short* __restrict__ ybuf,
    const int* __restrict__ inv, float* __restrict__ out) {
  int t = blockIdx.x;
  int4 iv = ((const int4*)inv)[t];
  const ushort4* y0 = (const ushort4*)(ybuf + (size_t)iv.x * D_);
  const ushort4* y1 = (const ushort4*)(ybuf + (size_t)iv.y * D_);
  const ushort4* y2 = (const ushort4*)(ybuf + (size_t)iv.z * D_);
  const ushort4* y3 = (const ushort4*)(ybuf + (size_t)iv.w * D_);
  const float4* xr = (const float4*)(x + (size_t)t * D_);
  float4* orow = (float4*)(out + (size_t)t * D_);
#pragma unroll
  for (int i = threadIdx.x; i < D_ / 4; i += 256) {
    float4 v = xr[i];
    ushort4 a = y0[i], b = y1[i], c = y2[i], d = y3[i];
    v.x += bf2f(a.x) + bf2f(b.x) + bf2f(c.x) + bf2f(d.x);
    v.y += bf2f(a.y) + bf2f(b.y) + bf2f(c.y) + bf2f(d.y);
    v.z += bf2f(a.z) + bf2f(b.z) + bf2f(c.z) + bf2f(d.z);
    v.w += bf2f(a.w) + bf2f(b.w) + bf2f(c.w) + bf2f(d.w);
    orow[i] = v;
  }
}

// ====== GEMM (R15/R16 proven): BM=BN=128, BK=64, 4 waves, 3 blocks/CU ======
// One tile per block; grid = worst-case tile count; HW backfill balances.
// Expert-outer, slab-mid, row-inner tile index; chunked XCD swizzle.
// NOTE: (256,4) was tried in R17 -> VGPR squeezed 76->64, massive scratch
// spills (WRITE 314MB), 2x regression. (256,3) is the occupancy sweet spot.

// ---------------- GEMM1: h = relu(X[ids] @ W1t^T + b1), bf16 out ----------------
__global__ __launch_bounds__(256, 3) void k_gemm1(
    const unsigned short* __restrict__ xb,   // [B][D] bf16
    const unsigned short* __restrict__ w1t,  // [E][H][D] bf16
    const float* __restrict__ b1,            // [E][H]
    const int* __restrict__ ids, const int* __restrict__ counts,
    unsigned short* __restrict__ hbuf)       // [sum cnt][H] bf16
{
  __shared__ unsigned short As[128 * 64];
  __shared__ unsigned short Bs[128 * 64];
  const int NS = H_ / 128;                   // 8 col slabs
  int cnts[E_], offsv[E_], rowt[E_], cumt[E_];
  int s = 0, tcum = 0;
#pragma unroll
  for (int e = 0; e < E_; e++) {
    cnts[e] = counts[e];
    offsv[e] = s; s += cnts[e];
    rowt[e] = (cnts[e] + 127) >> 7;
    cumt[e] = tcum; tcum += rowt[e] * NS;
  }
  int totalTiles = tcum;
  int bswz = (blockIdx.x & 7) * (gridDim.x >> 3) + (blockIdx.x >> 3);
  if (bswz >= totalTiles) return;
  int tile = bswz;
  int tid = threadIdx.x, lane = tid & 63, wid = tid >> 6;
  int wr = wid >> 1, wc = wid & 1;
  int cr = lane >> 3, slot = lane & 7;
  int sw = (slot ^ cr) << 3;
  int hi = lane >> 4, cl = lane & 15;

  int e = 0;
  while (e < E_ - 1 && tile >= cumt[e + 1]) e++;
  int local = tile - cumt[e];
  int slab = local / rowt[e];
  int rt = local - slab * rowt[e];
  int n0 = slab << 7;
  int cnt = cnts[e];
  int r0 = rt << 7;

  const unsigned short* a_src[4];
  const unsigned short* b_src[4];
  const unsigned short* wbase = w1t + (size_t)e * H_ * D_;
#pragma unroll
  for (int i = 0; i < 4; i++) {
    int chunk = wid * 4 + i;
    int rr = r0 + chunk * 8 + cr;
    int rc = min(rr, cnt - 1);
    int tok = ids[e * CAP + rc];
    a_src[i] = xb + (size_t)tok * D_ + sw;
    b_src[i] = wbase + (size_t)(n0 + chunk * 8 + cr) * D_ + sw;
  }
  f32x4_t acc[4][4];
#pragma unroll
  for (int m = 0; m < 4; m++)
#pragma unroll
    for (int n = 0; n < 4; n++) acc[m][n] = (f32x4_t){0.f, 0.f, 0.f, 0.f};

  for (int kt = 0; kt < D_; kt += 64) {
#pragma unroll
    for (int i = 0; i < 4; i++) {
      gld16(a_src[i] + kt, As + (wid * 4 + i) * 512);
      gld16(b_src[i] + kt, Bs + (wid * 4 + i) * 512);
    }
    __syncthreads();
#pragma unroll
    for (int kb = 0; kb < 2; kb++) {
      bf16x8_t af[4], bfr[4];
#pragma unroll
      for (int m = 0; m < 4; m++) {
        int row = wr * 64 + m * 16 + (lane & 15);
        int ss = (kb * 4 + (lane >> 4)) ^ (row & 7);
        af[m] = *(const bf16x8_t*)(As + row * 64 + ss * 8);
      }
#pragma unroll
      for (int n = 0; n < 4; n++) {
        int row = wc * 64 + n * 16 + (lane & 15);
        int ss = (kb * 4 + (lane >> 4)) ^ (row & 7);
        bfr[n] = *(const bf16x8_t*)(Bs + row * 64 + ss * 8);
      }
#pragma unroll
      for (int m = 0; m < 4; m++)
#pragma unroll
        for (int n = 0; n < 4; n++)
          acc[m][n] = __builtin_amdgcn_mfma_f32_16x16x32_bf16(af[m], bfr[n], acc[m][n], 0, 0, 0);
    }
    __syncthreads();
  }
  int offe = offsv[e];
  float bias[4];
#pragma unroll
  for (int n = 0; n < 4; n++)
    bias[n] = b1[e * H_ + n0 + wc * 64 + n * 16 + cl];
#pragma unroll
  for (int m = 0; m < 4; m++)
#pragma unroll
    for (int j = 0; j < 4; j++) {
      int sr = r0 + wr * 64 + m * 16 + hi * 4 + j;
      if (sr < cnt) {
        size_t rowb = (size_t)(offe + sr) * H_;
#pragma unroll
        for (int n = 0; n < 4; n++) {
          int col = n0 + wc * 64 + n * 16 + cl;
          float v = acc[m][n][j] + bias[n];
          v = v > 0.f ? v : 0.f;
          hbuf[rowb + col] = f2bf(v);
        }
      }
    }
}

// ------ GEMM2: ybuf[gslot] = w * (h @ W2t^T + b2)  (bf16 streaming stores) ------
__global__ __launch_bounds__(256, 3) void k_gemm2(
    const unsigned short* __restrict__ hbuf, // [sum cnt][H] bf16
    const unsigned short* __restrict__ w2t,  // [E][D][H] bf16
    const float* __restrict__ b2,            // [E][D]
    const float* __restrict__ wts,
    const int* __restrict__ counts,
    unsigned short* __restrict__ ybuf)       // [sum cnt][D] bf16
{
  __shared__ unsigned short As[128 * 64];
  __shared__ unsigned short Bs[128 * 64];
  const int NS = D_ / 128;                   // 16 col slabs
  int cnts[E_], offsv[E_], rowt[E_], cumt[E_];
  int s = 0, tcum = 0;
#pragma unroll
  for (int e = 0; e < E_; e++) {
    cnts[e] = counts[e];
    offsv[e] = s; s += cnts[e];
    rowt[e] = (cnts[e] + 127) >> 7;
    cumt[e] = tcum; tcum += rowt[e] * NS;
  }
  int totalTiles = tcum;
  int bswz = (blockIdx.x & 7) * (gridDim.x >> 3) + (blockIdx.x >> 3);
  if (bswz >= totalTiles) return;
  int tile = bswz;
  int tid = threadIdx.x, lane = tid & 63, wid = tid >> 6;
  int wr = wid >> 1, wc = wid & 1;
  int cr = lane >> 3, slot = lane & 7;
  int sw = (slot ^ cr) << 3;
  int hi = lane >> 4, cl = lane & 15;

  int e = 0;
  while (e < E_ - 1 && tile >= cumt[e + 1]) e++;
  int local = tile - cumt[e];
  int slab = local / rowt[e];
  int rt = local - slab * rowt[e];
  int n0 = slab << 7;
  int cnt = cnts[e];
  int r0 = rt << 7;
  int offe = offsv[e];

  const unsigned short* a_src[4];
  const unsigned short* b_src[4];
  const unsigned short* wbase = w2t + (size_t)e * D_ * H_;
#pragma unroll
  for (int i = 0; i < 4; i++) {
    int chunk = wid * 4 + i;
    int rr = r0 + chunk * 8 + cr;
    int rc = min(rr, cnt - 1);
    a_src[i] = hbuf + (size_t)(offe + rc) * H_ + sw;
    b_src[i] = wbase + (size_t)(n0 + chunk * 8 + cr) * H_ + sw;
  }
  f32x4_t acc[4][4];
#pragma unroll
  for (int m = 0; m < 4; m++)
#pragma unroll
    for (int n = 0; n < 4; n++) acc[m][n] = (f32x4_t){0.f, 0.f, 0.f, 0.f};

  for (int kt = 0; kt < H_; kt += 64) {
#pragma unroll
    for (int i = 0; i < 4; i++) {
      gld16(a_src[i] + kt, As + (wid * 4 + i) * 512);
      gld16(b_src[i] + kt, Bs + (wid * 4 + i) * 512);
    }
    __syncthreads();
#pragma unroll
    for (int kb = 0; kb < 2; kb++) {
      bf16x8_t af[4], bfr[4];
#pragma unroll
      for (int m = 0; m < 4; m++) {
        int row = wr * 64 + m * 16 + (lane & 15);
        int ss = (kb * 4 + (lane >> 4)) ^ (row & 7);
        af[m] = *(const bf16x8_t*)(As + row * 64 + ss * 8);
      }
#pragma unroll
      for (int n = 0; n < 4; n++) {
        int row = wc * 64 + n * 16 + (lane & 15);
        int ss = (kb * 4 + (lane >> 4)) ^ (row & 7);
        bfr[n] = *(const bf16x8_t*)(Bs + row * 64 + ss * 8);
      }
#pragma unroll
      for (int m = 0; m < 4; m++)
#pragma unroll
        for (int n = 0; n < 4; n++)
          acc[m][n] = __builtin_amdgcn_mfma_f32_16x16x32_bf16(af[m], bfr[n], acc[m][n], 0, 0, 0);
    }
    __syncthreads();
  }
  float bias[4];
#pragma unroll
  for (int n = 0; n < 4; n++)
    bias[n] = b2[e * D_ + n0 + wc * 64 + n * 16 + cl];
#pragma unroll
  for (int m = 0; m < 4; m++)
#pragma unroll
    for (int j = 0; j < 4; j++) {
      int sr = r0 + wr * 64 + m * 16 + hi * 4 + j;
      if (sr < cnt) {
        float w = wts[e * CAP + sr];
        unsigned short* yrow = ybuf + (size_t)(offe + sr) * D_;
#pragma unroll
        for (int n = 0; n < 4; n++) {
          int col = n0 + wc * 64 + n * 16 + cl;
          yrow[col] = f2bf(w * (acc[m][n][j] + bias[n]));
        }
      }
    }
}

extern "C" void kernel_launch(void* const* d_in, const int* in_sizes, int n_in,
                              void* d_out, int out_size, void* d_ws, size_t ws_size,
                              hipStream_t stream) {
  const float* x  = (const float*)d_in[0];
  const float* W1 = (const float*)d_in[1];
  const float* b1 = (const float*)d_in[2];
  const float* W2 = (const float*)d_in[3];
  const float* b2 = (const float*)d_in[4];
  const float* Wr = (const float*)d_in[5];
  const float* br = (const float*)d_in[6];
  float* out = (float*)d_out;
  char* ws = (char*)d_ws;
  // workspace layout (~176.9 MiB total). ybuf ALIASES W1t (dead after gemm1).
  unsigned short* W1t  = (unsigned short*)(ws);                // 67108864 B [E][H][D] bf16
  unsigned short* ybuf = (unsigned short*)(ws);                // 67108864 B [16384][D] bf16
  unsigned short* W2t  = (unsigned short*)(ws + 67108864);     // 67108864 B [E][D][H] bf16
  unsigned short* xb   = (unsigned short*)(ws + 134217728);    // 16777216 B [B][D] bf16
  unsigned short* hb   = (unsigned short*)(ws + 150994944);    // 33554432 B [B*K][H] bf16
  int*   ids    = (int*)  (ws + 184549376);                    // 262144 B
  float* wts    = (float*)(ws + 184811520);                    // 262144 B
  int*   counts = (int*)  (ws + 185073664);                    // 64 B
  float* wrT    = (float*)(ws + 185073728);                    // 131072 B [E][D] f32
  int*   tops   = (int*)  (ws + 185204800);                    // 65536 B [B][4]
  float* topw   = (float*)(ws + 185270336);                    // 65536 B [B][4]
  int*   inv    = (int*)  (ws + 185335872);                    // 65536 B [B][4]

  k_prepw<<<8320, 256, 0, stream>>>(Wr, wrT, W1, W1t, W2, W2t);
  k_router<<<1024, 256, 0, stream>>>(x, wrT, br, xb, tops, topw);
  k_build<<<16, 256, 0, stream>>>(tops, topw, counts, ids, wts, inv);
  k_gemm1<<<1152, 256, 0, stream>>>(xb, W1t, b1, ids, counts, hb);
  k_gemm2<<<2304, 256, 0, stream>>>(hb, W2t, b2, wts, counts, ybuf);
  k_gather<<<4096, 256, 0, stream>>>(x, ybuf, inv, out);
}